// Round 15
// baseline (198.942 us; speedup 1.0000x reference)
//
#include <hip/hip_runtime.h>
#include <hip/hip_bf16.h>
#include <stdint.h>

// MultiHeadAttention: B=2, P=2048, D_MODEL=1024, H=16, D=64, causal.
//
// R26: attn_k load balance solved WITHIN the block (no cross-block sync,
// no placement sensitivity): waves 0-1 own 64 q-rows of qA=15-p, waves
// 2-3 own 64 q-rows of qB=p; K/V staging shared across all 4 waves; loop
// runs qA's kv range (32-2p iters); B-waves compute only for kt<2p+2 and
// co-stage afterwards. Every block = exactly 64x34 row-iters -> uniform
// wall time (~17 full-rate iters), killing the up-to-30-iter solo tail of
// the (t,15-t) co-residency pairing (R21-diagnosed; R22/R23's cross-block
// combine was scheduler-fragile). Grid stays (16,16,2)=512=2/CU; VGPR
// unchanged (split is across waves). Staged tiles 17408->12800.
// R25 lesson kept: GEMMs at 3 blocks/CU gain nothing from counted-vmcnt
// (TLP already covers the drain) — qkv/out/prep unchanged.

typedef __bf16 bf16x8 __attribute__((ext_vector_type(8)));
typedef float f32x4 __attribute__((ext_vector_type(4)));
typedef float f32x16 __attribute__((ext_vector_type(16)));
typedef unsigned short u16;

__device__ __forceinline__ u16 f2bf(float f) {
  unsigned u = __float_as_uint(f);
  u += 0x7fffu + ((u >> 16) & 1u);
  return (u16)(u >> 16);
}

__device__ __forceinline__ uint32_t cvtpk(float lo, float hi) {
  uint32_t r;
  asm("v_cvt_pk_bf16_f32 %0, %1, %2" : "=v"(r) : "v"(lo), "v"(hi));
  return r;
}

__device__ __forceinline__ void pl32swap(uint32_t& a, uint32_t& b) {
  asm volatile("v_permlane32_swap_b32 %0, %1" : "+v"(a), "+v"(b));
}

// raw 2^x — domain bounded (|score| < ~40, masked = -1e30 -> 0)
__device__ __forceinline__ float fexp2(float x) {
  float r;
  asm("v_exp_f32 %0, %1" : "=v"(r) : "v"(x));
  return r;
}

// ---- direct global->LDS DMA, 16B per lane (dest = wave-uniform base + lane*16) ----
__device__ __forceinline__ void gload16(const u16* g, u16* l) {
  __builtin_amdgcn_global_load_lds(
      (__attribute__((address_space(1))) void*)(g),
      (__attribute__((address_space(3))) void*)(l), 16, 0, 0);
}

// ====== fused prep: [0,2048) xcvt; [2048,2816) qkv W transpose;
// ====== [2816,3072) Wo transpose. ======
__global__ __launch_bounds__(256) void prep_k(const float* __restrict__ X,
                                              const float* __restrict__ Wq,
                                              const float* __restrict__ Wk,
                                              const float* __restrict__ Wv,
                                              const float* __restrict__ Wo,
                                              u16* __restrict__ Xb,
                                              u16* __restrict__ WqT,
                                              u16* __restrict__ WoT) {
  __shared__ u16 tile[64][80];
  int bid = blockIdx.x, t = threadIdx.x;

  if (bid < 2048) {  // ---- X f32 -> bf16, 8 elems/thread ----
    int i = (bid * 256 + t) * 8;
    float4 f0 = *reinterpret_cast<const float4*>(X + i);
    float4 f1 = *reinterpret_cast<const float4*>(X + i + 4);
    u16 tmp[8] = {f2bf(f0.x), f2bf(f0.y), f2bf(f0.z), f2bf(f0.w),
                  f2bf(f1.x), f2bf(f1.y), f2bf(f1.z), f2bf(f1.w)};
    *reinterpret_cast<uint4*>(Xb + i) = *reinterpret_cast<uint4*>(tmp);
    return;
  }

  if (bid < 2816) {  // ---- q/k/v weight transpose: [1024][64] -> [64][1024] ----
    int tq = bid - 2048;
    int rb = tq & 15, z = tq >> 4;
    int sel = z >> 4, head = z & 15;
    const float* W = (sel == 0) ? Wq : (sel == 1 ? Wk : Wv);
    const float* ip = W + (size_t)head * 65536;
    u16* op = WqT + (size_t)sel * 1048576 + (size_t)head * 65536;
    int r0 = rb * 64;
    int r = t >> 2, cb = (t & 3) * 16;
    const float4* src = reinterpret_cast<const float4*>(ip + (size_t)(r0 + r) * 64 + cb);
    u16 tmp[16];
#pragma unroll
    for (int v = 0; v < 4; v++) {
      float4 f = src[v];
      tmp[v * 4 + 0] = f2bf(f.x);
      tmp[v * 4 + 1] = f2bf(f.y);
      tmp[v * 4 + 2] = f2bf(f.z);
      tmp[v * 4 + 3] = f2bf(f.w);
    }
    *reinterpret_cast<uint4*>(&tile[r][cb]) = *reinterpret_cast<uint4*>(&tmp[0]);
    *reinterpret_cast<uint4*>(&tile[r][cb + 8]) = *reinterpret_cast<uint4*>(&tmp[8]);
    __syncthreads();
    int c = t >> 2, rbq = (t & 3) * 16;
    uint4 outv[2];
    u16* tp = reinterpret_cast<u16*>(outv);
#pragma unroll
    for (int j = 0; j < 16; j++) tp[j] = tile[rbq + j][c];
    uint4* dst = reinterpret_cast<uint4*>(op + (size_t)c * 1024 + r0 + rbq);
    dst[0] = outv[0];
    dst[1] = outv[1];
    return;
  }

  {  // ---- Wo transpose ----
    int tc = bid - 2816;
    int r0 = (tc & 15) * 64;
    int c0 = (tc >> 4) * 64;
    int r = t >> 2, cb = (t & 3) * 16;
    const float4* src = reinterpret_cast<const float4*>(Wo + (size_t)(r0 + r) * 1024 + c0 + cb);
    u16 tmp[16];
#pragma unroll
    for (int v = 0; v < 4; v++) {
      float4 f = src[v];
      tmp[v * 4 + 0] = f2bf(f.x);
      tmp[v * 4 + 1] = f2bf(f.y);
      tmp[v * 4 + 2] = f2bf(f.z);
      tmp[v * 4 + 3] = f2bf(f.w);
    }
    *reinterpret_cast<uint4*>(&tile[r][cb]) = *reinterpret_cast<uint4*>(&tmp[0]);
    *reinterpret_cast<uint4*>(&tile[r][cb + 8]) = *reinterpret_cast<uint4*>(&tmp[8]);
    __syncthreads();
    int c = t >> 2, rbq = (t & 3) * 16;
    uint4 outv[2];
    u16* tp = reinterpret_cast<u16*>(outv);
#pragma unroll
    for (int j = 0; j < 16; j++) tp[j] = tile[rbq + j][c];
    uint4* dst = reinterpret_cast<uint4*>(WoT + (size_t)(c0 + c) * 1024 + r0 + rbq);
    dst[0] = outv[0];
    dst[1] = outv[1];
  }
}

// ====== QKV GEMM: 128x128, BK=32, 3-buffer counted-vmcnt (R25, 3 blk/CU) ======
__global__ __launch_bounds__(256) void qkv_gemm128_k(const u16* __restrict__ A,
                                                     const u16* __restrict__ BT,
                                                     u16* __restrict__ Q,
                                                     u16* __restrict__ K,
                                                     u16* __restrict__ VT2) {
  __shared__ __align__(16) u16 As[3][128][32];
  __shared__ __align__(16) u16 Bs[3][128][32];
  const float QSCALE = 0.125f * 1.44269504088896340736f;  // (1/sqrt(64))*log2(e)
  int m0 = blockIdx.x * 128, n0 = blockIdx.y * 128;
  int t = threadIdx.x, l = t & 63;
  int w = t >> 6, wm = w & 1, wn = w >> 1;
  int l15 = l & 15, q4 = l >> 4;
  int g = ((l & 3) - (l >> 3)) & 3;
  size_t lsrc = (size_t)(l >> 2) * 1024 + (size_t)(g * 8);
  const u16* ga = A + (size_t)(m0 + w * 32) * 1024 + lsrc;
  const u16* gb = BT + (size_t)(n0 + w * 32) * 1024 + lsrc;
  int rch = ((q4 + (l15 >> 1)) & 3) * 8;

  f32x4 acc[4][4];
  f32x4 z4 = {0.f, 0.f, 0.f, 0.f};
#pragma unroll
  for (int mi = 0; mi < 4; mi++)
#pragma unroll
    for (int nt = 0; nt < 4; nt++) acc[mi][nt] = z4;

  auto stage = [&](int buf, int k0) {  // 4 gloads/wave
    gload16(ga + k0, &As[buf][w * 32][0]);
    gload16(ga + (size_t)16 * 1024 + k0, &As[buf][w * 32 + 16][0]);
    gload16(gb + k0, &Bs[buf][w * 32][0]);
    gload16(gb + (size_t)16 * 1024 + k0, &Bs[buf][w * 32 + 16][0]);
  };

  stage(0, 0);
  stage(1, 32);

  int cur = 0;
  for (int step = 0; step < 32; step++) {
    if (step + 1 < 32)
      asm volatile("s_waitcnt vmcnt(4)" ::: "memory");
    else
      asm volatile("s_waitcnt vmcnt(0)" ::: "memory");
    __builtin_amdgcn_s_barrier();
    if (step + 2 < 32) {
      int nb = cur + 2; if (nb >= 3) nb -= 3;
      stage(nb, (step + 2) * 32);
    }
    bf16x8 af[4], bfr[4];
#pragma unroll
    for (int mi = 0; mi < 4; mi++)
      af[mi] = *reinterpret_cast<const bf16x8*>(&As[cur][wm * 64 + mi * 16 + l15][rch]);
#pragma unroll
    for (int nt = 0; nt < 4; nt++)
      bfr[nt] = *reinterpret_cast<const bf16x8*>(&Bs[cur][wn * 64 + nt * 16 + l15][rch]);
    __builtin_amdgcn_s_setprio(1);
#pragma unroll
    for (int mi = 0; mi < 4; mi++)
#pragma unroll
      for (int nt = 0; nt < 4; nt++)
        acc[mi][nt] = __builtin_amdgcn_mfma_f32_16x16x32_bf16(af[mi], bfr[nt], acc[mi][nt], 0, 0, 0);
    __builtin_amdgcn_s_setprio(0);
    cur = (cur == 2) ? 0 : cur + 1;
  }

#pragma unroll
  for (int mi = 0; mi < 4; mi++) {
#pragma unroll
    for (int nt = 0; nt < 4; nt++) {
#pragma unroll
      for (int r = 0; r < 4; r++) {
        int m = m0 + wm * 64 + mi * 16 + q4 * 4 + r;
        int n = n0 + wn * 64 + nt * 16 + l15;
        int wsel = n >> 10, h = (n >> 6) & 15, d = n & 63;
        int b = m >> 11, p = m & 2047;
        size_t bh = (size_t)(b * 16 + h);
        float v = acc[mi][nt][r];
        if (wsel == 0)
          Q[(bh * 2048 + p) * 64 + d] = f2bf(v * QSCALE);
        else if (wsel == 1)
          K[(bh * 2048 + p) * 64 + d] = f2bf(v);
        else
          VT2[((bh * 32 + (p >> 6)) * 64 + d) * 64 + (p & 63)] = f2bf(v);
      }
    }
  }
}

// ====== OUT GEMM: 128x64 tile, BK=32, 3-buffer counted-vmcnt (36KB LDS) ======
__global__ __launch_bounds__(256) void out_gemm64_k(const u16* __restrict__ A,
                                                    const u16* __restrict__ BT,
                                                    float* __restrict__ O) {
  __shared__ __align__(16) u16 As[3][128][32];
  __shared__ __align__(16) u16 Bs[3][64][32];
  int m0 = blockIdx.x * 128, n0 = blockIdx.y * 64;
  int t = threadIdx.x, l = t & 63;
  int w = t >> 6, wm = w >> 1, wn = w & 1;
  int l15 = l & 15, q4 = l >> 4;
  int g = ((l & 3) - (l >> 3)) & 3;
  size_t lsrc = (size_t)(l >> 2) * 1024 + (size_t)(g * 8);
  const u16* ga = A + (size_t)(m0 + w * 32) * 1024 + lsrc;
  const u16* gb = BT + (size_t)(n0 + w * 16) * 1024 + lsrc;
  int rch = ((q4 + (l15 >> 1)) & 3) * 8;

  f32x4 acc[4][2];
  f32x4 z4 = {0.f, 0.f, 0.f, 0.f};
#pragma unroll
  for (int mi = 0; mi < 4; mi++)
#pragma unroll
    for (int nt = 0; nt < 2; nt++) acc[mi][nt] = z4;

  auto stage = [&](int buf, int k0) {  // 3 gloads/wave
    gload16(ga + k0, &As[buf][w * 32][0]);
    gload16(ga + (size_t)16 * 1024 + k0, &As[buf][w * 32 + 16][0]);
    gload16(gb + k0, &Bs[buf][w * 16][0]);
  };

  stage(0, 0);
  stage(1, 32);

  int cur = 0;
  for (int step = 0; step < 32; step++) {
    if (step + 1 < 32)
      asm volatile("s_waitcnt vmcnt(3)" ::: "memory");
    else
      asm volatile("s_waitcnt vmcnt(0)" ::: "memory");
    __builtin_amdgcn_s_barrier();
    if (step + 2 < 32) {
      int nb = cur + 2; if (nb >= 3) nb -= 3;
      stage(nb, (step + 2) * 32);
    }
    bf16x8 af[4], bfr[2];
#pragma unroll
    for (int mi = 0; mi < 4; mi++)
      af[mi] = *reinterpret_cast<const bf16x8*>(&As[cur][wm * 64 + mi * 16 + l15][rch]);
#pragma unroll
    for (int nt = 0; nt < 2; nt++)
      bfr[nt] = *reinterpret_cast<const bf16x8*>(&Bs[cur][wn * 32 + nt * 16 + l15][rch]);
    __builtin_amdgcn_s_setprio(1);
#pragma unroll
    for (int mi = 0; mi < 4; mi++)
#pragma unroll
      for (int nt = 0; nt < 2; nt++)
        acc[mi][nt] = __builtin_amdgcn_mfma_f32_16x16x32_bf16(af[mi], bfr[nt], acc[mi][nt], 0, 0, 0);
    __builtin_amdgcn_s_setprio(0);
    cur = (cur == 2) ? 0 : cur + 1;
  }

#pragma unroll
  for (int mi = 0; mi < 4; mi++) {
#pragma unroll
    for (int nt = 0; nt < 2; nt++) {
#pragma unroll
      for (int r = 0; r < 4; r++) {
        int m = m0 + wm * 64 + mi * 16 + q4 * 4 + r;
        int n = n0 + wn * 32 + nt * 16 + l15;
        O[(size_t)m * 1024 + n] = acc[mi][nt][r];
      }
    }
  }
}

// ---- flash attention: within-block q-pairing, 32x32 swapped-QK^T,
// in-reg softmax, 3-buffer counted-vmcnt pipeline ----
// grid (16,16,2): pr -> pair p = pr&7 (qA=15-p, qB=p), qhalf = pr>>3.
// Waves 0-1: 64 rows of qA (the long kv range, runs the full loop);
// waves 2-3: 64 rows of qB (computes only kt < 2p+2, co-stages after).
// All blocks do exactly 64x34 row-iters -> uniform wall time.
__global__ __launch_bounds__(256) void attn_k(const u16* __restrict__ Q,
                                              const u16* __restrict__ K,
                                              const u16* __restrict__ VT2,
                                              u16* __restrict__ A) {
  __shared__ __align__(16) u16 Ks[3][64][64];
  __shared__ __align__(16) u16 Vs[3][64][64];
  int pr = blockIdx.x, h = blockIdx.y, b = blockIdx.z;
  int p = pr & 7, qhalf = pr >> 3;
  int qA = 15 - p, qB = p;
  int nktA = 2 * qA + 2;                     // 18..32 (the loop length)
  int nktB = 2 * qB + 2;                     // 2..16
  size_t bh = (size_t)(b * 16 + h);
  const u16* Qp = Q + bh * 2048 * 64;
  const u16* Kp = K + bh * 2048 * 64;
  const u16* Vt = VT2 + bh * 32 * 64 * 64;   // [kt][d(64)][pc(64)]
  int t = threadIdx.x, l = t & 63, w = t >> 6;
  int l31 = l & 31, hi = l >> 5;
  int r8 = l >> 3, cs = ((l & 7) ^ r8) * 8;
  int swz = l31 & 7;
  const float NEG = -1e30f;
  bool isA = (w < 2);
  int qt_w = isA ? qA : qB;                  // this wave's q-tile
  int nkt_w = isA ? nktA : nktB;             // this wave's compute range
  const u16* kbase = Kp + (size_t)(w * 16 + r8) * 64 + cs;
  const u16* vbase = Vt + (size_t)(w * 16 + r8) * 64 + cs;
  int qrow = qt_w * 128 + qhalf * 64 + (w & 1) * 32 + l31;

  uint32_t onesw[4] = {0x3F803F80u, 0x3F803F80u, 0x3F803F80u, 0x3F803F80u};
  bf16x8 onesb = *reinterpret_cast<const bf16x8*>(onesw);

  bf16x8 qb[4];
#pragma unroll
  for (int kc = 0; kc < 4; kc++)
    qb[kc] = *reinterpret_cast<const bf16x8*>(Qp + (size_t)qrow * 64 + kc * 16 + hi * 8);

  f32x16 accO[2], rs_acc;
#pragma unroll
  for (int dh = 0; dh < 2; dh++)
#pragma unroll
    for (int r = 0; r < 16; r++) accO[dh][r] = 0.f;
#pragma unroll
  for (int r = 0; r < 16; r++) rs_acc[r] = 0.f;

  auto stageKV = [&](int buf, int kt) {  // 4 gloads/wave, fixed order K0,K1,V0,V1
    size_t off = (size_t)kt * 4096;
#pragma unroll
    for (int j = 0; j < 2; j++)
      gload16(kbase + off + j * 512, &Ks[buf][w * 16 + j * 8][0]);
#pragma unroll
    for (int j = 0; j < 2; j++)
      gload16(vbase + off + j * 512, &Vs[buf][w * 16 + j * 8][0]);
  };

  // prologue: issue tiles 0 and 1 (nktA >= 18, always valid)
  stageKV(0, 0);
  stageKV(1, 1);

  int cur = 0;
  for (int kt = 0; kt < nktA; kt++) {
    if (kt + 1 < nktA)
      asm volatile("s_waitcnt vmcnt(4)" ::: "memory");
    else
      asm volatile("s_waitcnt vmcnt(0)" ::: "memory");
    __builtin_amdgcn_s_barrier();   // all waves: tile kt landed, kt-1 reads done
    if (kt + 2 < nktA) {            // refill the buffer last read at kt-1
      int nb = cur + 2; if (nb >= 3) nb -= 3;
      stageKV(nb, kt + 2);
    }

    if (kt < nkt_w) {  // wave-uniform guard: B-waves co-stage only, after 2p+2
      f32x16 st[2];
#pragma unroll
      for (int kvh = 0; kvh < 2; kvh++)
#pragma unroll
        for (int r = 0; r < 16; r++) st[kvh][r] = 0.f;
      __builtin_amdgcn_s_setprio(1);
#pragma unroll
      for (int kc = 0; kc < 4; kc++) {
        bf16x8 ka0 = *reinterpret_cast<const bf16x8*>(
            &Ks[cur][l31][((2 * kc + hi) ^ swz) * 8]);
        bf16x8 ka1 = *reinterpret_cast<const bf16x8*>(
            &Ks[cur][32 + l31][((2 * kc + hi) ^ swz) * 8]);
        st[0] = __builtin_amdgcn_mfma_f32_32x32x16_bf16(ka0, qb[kc], st[0], 0, 0, 0);
        st[1] = __builtin_amdgcn_mfma_f32_32x32x16_bf16(ka1, qb[kc], st[1], 0, 0, 0);
      }
      __builtin_amdgcn_s_setprio(0);

      if (kt >= 2 * qt_w) {  // causal mask (last two kv tiles of this wave's range)
        int kvb = kt * 64;
#pragma unroll
        for (int kvh = 0; kvh < 2; kvh++)
#pragma unroll
          for (int r = 0; r < 16; r++) {
            int kv = kvb + kvh * 32 + (r & 3) + 8 * (r >> 2) + 4 * hi;
            if (kv > qrow) st[kvh][r] = NEG;
          }
      }

      // fixed-max softmax numerator (log2-domain); masked -> 0
#pragma unroll
      for (int kvh = 0; kvh < 2; kvh++)
#pragma unroll
        for (int r = 0; r < 16; r++) st[kvh][r] = fexp2(st[kvh][r]);

      // P -> bf16 PV A-fragments in-register
      bf16x8 pa[4];
#pragma unroll
      for (int ks = 0; ks < 4; ks++) {
        const f32x16& pp = st[ks >> 1];
        const int s8 = (ks & 1) * 8;
        uint32_t x0 = cvtpk(pp[s8 + 0], pp[s8 + 1]);
        uint32_t x1 = cvtpk(pp[s8 + 2], pp[s8 + 3]);
        uint32_t y0 = cvtpk(pp[s8 + 4], pp[s8 + 5]);
        uint32_t y1 = cvtpk(pp[s8 + 6], pp[s8 + 7]);
        pl32swap(x0, y0);
        pl32swap(x1, y1);
        uint32_t wds[4] = {x0, x1, y0, y1};
        pa[ks] = *reinterpret_cast<const bf16x8*>(wds);
      }

      __builtin_amdgcn_s_setprio(1);
#pragma unroll
      for (int ks = 0; ks < 4; ks++)
        rs_acc = __builtin_amdgcn_mfma_f32_32x32x16_bf16(pa[ks], onesb, rs_acc, 0, 0, 0);
#pragma unroll
      for (int dh = 0; dh < 2; dh++)
#pragma unroll
        for (int ks = 0; ks < 4; ks++) {
          bf16x8 vb = *reinterpret_cast<const bf16x8*>(
              &Vs[cur][dh * 32 + l31][((2 * ks + hi) ^ swz) * 8]);
          accO[dh] = __builtin_amdgcn_mfma_f32_32x32x16_bf16(pa[ks], vb, accO[dh], 0, 0, 0);
        }
      __builtin_amdgcn_s_setprio(0);
    }

    cur = (cur == 2) ? 0 : cur + 1;
  }

  // ---- epilogue: rs_acc[r] is the row-sum for accO[.][r]'s q-row ----
#pragma unroll
  for (int r = 0; r < 16; r++) {
    float inv = 1.f / rs_acc[r];
    int ql = (r & 3) + 8 * (r >> 2) + 4 * hi;
    int prow = qt_w * 128 + qhalf * 64 + (w & 1) * 32 + ql;
    size_t base = ((size_t)(b * 2048 + prow)) * 1024 + h * 64;
    A[base + l31] = f2bf(accO[0][r] * inv);
    A[base + 32 + l31] = f2bf(accO[1][r] * inv);
  }
}

extern "C" void kernel_launch(void* const* d_in, const int* in_sizes, int n_in,
                              void* d_out, int out_size, void* d_ws, size_t ws_size,
                              hipStream_t stream) {
  const float* X  = (const float*)d_in[0];  // residual_stream [2][2048][1024]
  const float* Wq = (const float*)d_in[1];  // weight_query [16][1024][64]
  const float* Wk = (const float*)d_in[2];  // weight_key   [16][1024][64]
  const float* Wv = (const float*)d_in[3];  // weight_value [16][1024][64]
  const float* Wo = (const float*)d_in[4];  // weight_out   [1024][1024]
  float* out = (float*)d_out;               // [2][2048][1024] f32

  u16* ws = (u16*)d_ws;
  u16* WqT = ws;                    // [16][64][1024] x3 contiguous
  u16* WoT = WqT + 3145728;         // [1024][1024]
  u16* Xb  = WoT + 1048576;         // [4096][1024] bf16 (dead after qkv)
  u16* Qb  = Xb + 4194304;          // [32][2048][64]
  u16* Kb  = Qb + 4194304;          // [32][2048][64]
  u16* VT2 = Kb + 4194304;          // [32][32][64][64] tile-blocked
  u16* Ab  = Xb;                    // aliases Xb; total 40 MB

  prep_k<<<dim3(3072), 256, 0, stream>>>(X, Wq, Wk, Wv, Wo, Xb, WqT, WoT);
  qkv_gemm128_k<<<dim3(32, 24), 256, 0, stream>>>(Xb, WqT, Qb, Kb, VT2);
  attn_k<<<dim3(16, 16, 2), 256, 0, stream>>>(Qb, Kb, VT2, Ab);
  out_gemm64_k<<<dim3(32, 16), 256, 0, stream>>>(Ab, WoT, out);
}